// Round 4
// baseline (451.445 us; speedup 1.0000x reference)
//
#include <hip/hip_runtime.h>

#define NN 100000
#define NE 1600000
#define HALF 50000

typedef float f4 __attribute__((ext_vector_type(4)));
typedef int i4 __attribute__((ext_vector_type(4)));
typedef unsigned short us4 __attribute__((ext_vector_type(4)));

__device__ __forceinline__ float bf2f(unsigned short v) {
    return __builtin_bit_cast(float, ((unsigned)v) << 16);
}
__device__ __forceinline__ unsigned short f2bf(float f) {
    unsigned u = __builtin_bit_cast(unsigned, f);
    return (unsigned short)((u + 0x7FFF + ((u >> 16) & 1)) >> 16);
}

// ---------------- input -> bf16 gather table ----------------
__global__ __launch_bounds__(256) void k_convert(const f4* __restrict__ in4,
                                                 us4* __restrict__ out4) {
    int t = blockIdx.x * blockDim.x + threadIdx.x;
    if (t < NN * 32 / 4) {
        f4 v = in4[t];
        us4 o;
#pragma unroll
        for (int c = 0; c < 4; ++c) o[c] = f2bf(v[c]);
        out4[t] = o;
    }
}

// ---------------- CSR build (src-half partitioned) ----------------
__global__ __launch_bounds__(256) void k_count(const i4* __restrict__ dst4,
                                               const i4* __restrict__ src4,
                                               int* __restrict__ degA,
                                               int* __restrict__ degB,
                                               us4* __restrict__ rank4) {
    int t = blockIdx.x * blockDim.x + threadIdx.x;
    if (t < NE / 4) {
        i4 d = dst4[t];
        i4 s = src4[t];
        us4 r;
#pragma unroll
        for (int i = 0; i < 4; ++i) {
            int* ctr = (s[i] < HALF) ? &degA[d[i]] : &degB[d[i]];
            r[i] = (unsigned short)atomicAdd(ctr, 1);
        }
        rank4[t] = r;
    }
}

__global__ void k_scan1(const int* __restrict__ degA, const int* __restrict__ degB,
                        int* __restrict__ offs, int* __restrict__ bsums) {
    __shared__ int ts[256];
    int b = blockIdx.x, t = threadIdx.x;
    int base = b * 1024 + t * 4;
    int v[4];
    int s = 0;
#pragma unroll
    for (int i = 0; i < 4; ++i) {
        int idx = base + i;
        v[i] = (idx < NN) ? (degA[idx] + degB[idx]) : 0;
        s += v[i];
    }
    ts[t] = s;
    __syncthreads();
    for (int off = 1; off < 256; off <<= 1) {
        int x = (t >= off) ? ts[t - off] : 0;
        __syncthreads();
        ts[t] += x;
        __syncthreads();
    }
    int excl = ts[t] - s;
#pragma unroll
    for (int i = 0; i < 4; ++i) {
        int idx = base + i;
        if (idx < NN) offs[idx] = excl;
        excl += v[i];
    }
    if (t == 255) bsums[b] = ts[255];
}

__global__ void k_scan2(int* __restrict__ bsums, int nb) {
    int lane = threadIdx.x;
    int v0 = (lane < nb) ? bsums[lane] : 0;
    int v1 = (64 + lane < nb) ? bsums[64 + lane] : 0;
    int s0 = v0, s1 = v1;
    for (int o = 1; o < 64; o <<= 1) {
        int t0 = __shfl_up(s0, o, 64);
        int t1 = __shfl_up(s1, o, 64);
        if (lane >= o) { s0 += t0; s1 += t1; }
    }
    int tot0 = __shfl(s0, 63, 64);
    if (lane < nb) bsums[lane] = s0 - v0;
    if (64 + lane < nb) bsums[64 + lane] = tot0 + s1 - v1;
}

// finalize offs; bnd = offs + degA; dinv (over degB slot, total degree)
__global__ void k_scan3(int* __restrict__ offs, const int* __restrict__ bsums,
                        const int* __restrict__ degA, int* __restrict__ degB,
                        int* __restrict__ bnd, float* __restrict__ dinv) {
    int i = blockIdx.x * blockDim.x + threadIdx.x;
    if (i < NN) {
        int o = offs[i] + bsums[i >> 10];
        offs[i] = o;
        int da = degA[i];
        int dg = da + degB[i];
        bnd[i] = o + da;
        dinv[i] = (dg > 0) ? (1.0f / (float)dg) : 0.0f;
        if (i == 0) offs[NN] = NE;
    }
}

// atomic-free scatter: src<HALF edges first within each dst segment
__global__ __launch_bounds__(256) void k_scatter(const i4* __restrict__ src4,
                                                 const i4* __restrict__ dst4,
                                                 const us4* __restrict__ rank4,
                                                 const int* __restrict__ offs,
                                                 const int* __restrict__ degA,
                                                 int* __restrict__ ssrc) {
    int t = blockIdx.x * blockDim.x + threadIdx.x;
    if (t < NE / 4) {
        i4 s = src4[t];
        i4 d = dst4[t];
        us4 r = rank4[t];
#pragma unroll
        for (int i = 0; i < 4; ++i) {
            int base = offs[d[i]] + ((s[i] < HALF) ? 0 : degA[d[i]]);
            ssrc[base + (int)r[i]] = s[i];
        }
    }
}

// ---------------- SAGE pass A: gather src<HALF, write fp32 partials --------
__global__ __launch_bounds__(256) void k_sageA(
    const unsigned short* __restrict__ gt, const int* __restrict__ offs,
    const int* __restrict__ bnd, const int* __restrict__ ssrc,
    float* __restrict__ pacc) {
    const int lane = threadIdx.x & 63;
    const int fq = lane & 7;
    const int slot = lane >> 3;
    const int stride = gridDim.x * 4;

    for (int node = blockIdx.x * 4 + (threadIdx.x >> 6); node < NN; node += stride) {
        const int e0 = offs[node], e1 = bnd[node];
        f4 acc = (f4)0.0f;
        int e = e0 + slot;
        for (; e + 8 < e1; e += 16) {
            int s0 = ssrc[e];
            int s1 = ssrc[e + 8];
            us4 a = *(const us4*)(gt + s0 * 32 + fq * 4);
            us4 b = *(const us4*)(gt + s1 * 32 + fq * 4);
#pragma unroll
            for (int c = 0; c < 4; ++c) acc[c] += bf2f(a[c]) + bf2f(b[c]);
        }
        if (e < e1) {
            int s0 = ssrc[e];
            us4 a = *(const us4*)(gt + s0 * 32 + fq * 4);
#pragma unroll
            for (int c = 0; c < 4; ++c) acc[c] += bf2f(a[c]);
        }
#pragma unroll
        for (int m = 8; m <= 32; m <<= 1) {
#pragma unroll
            for (int c = 0; c < 4; ++c) acc[c] += __shfl_xor(acc[c], m, 64);
        }
        if (slot == 0) *(f4*)(pacc + node * 32 + fq * 4) = acc;
    }
}

// ---------------- SAGE pass B: gather src>=HALF, combine, sigmoid ----------
// SELF32: self-path from fp32 hinf (layer1) else from bf16 gt.
// OUTBF: write bf16 table, else fp32 out.
template <int OUTF, bool SELF32, bool OUTBF>
__global__ __launch_bounds__(256) void k_sageB(
    const float* __restrict__ hinf, const unsigned short* __restrict__ gt,
    const int* __restrict__ offs, const int* __restrict__ bnd,
    const int* __restrict__ ssrc, const float* __restrict__ dinv,
    const float* __restrict__ pacc,
    const float* __restrict__ Ws, const float* __restrict__ Wn,
    const float* __restrict__ bias,
    float* __restrict__ outf, unsigned short* __restrict__ outb) {
    __shared__ float sW[2][32 * OUTF];
    __shared__ float sB[OUTF];
    for (int i = threadIdx.x; i < 32 * OUTF; i += 256) {
        sW[0][i] = Ws[i];
        sW[1][i] = Wn[i];
    }
    if (threadIdx.x < OUTF) sB[threadIdx.x] = bias[threadIdx.x];
    __syncthreads();

    const int lane = threadIdx.x & 63;
    const int fq = lane & 7;
    const int slot = lane >> 3;
    const int half = lane >> 5;
    const float* wt = sW[half];
    const int j = lane & (OUTF - 1);
    const int stride = gridDim.x * 4;

    for (int node = blockIdx.x * 4 + (threadIdx.x >> 6); node < NN; node += stride) {
        const int e0 = bnd[node], e1 = offs[node + 1];
        f4 acc = (f4)0.0f;
        int e = e0 + slot;
        for (; e + 8 < e1; e += 16) {
            int s0 = ssrc[e];
            int s1 = ssrc[e + 8];
            us4 a = *(const us4*)(gt + s0 * 32 + fq * 4);
            us4 b = *(const us4*)(gt + s1 * 32 + fq * 4);
#pragma unroll
            for (int c = 0; c < 4; ++c) acc[c] += bf2f(a[c]) + bf2f(b[c]);
        }
        if (e < e1) {
            int s0 = ssrc[e];
            us4 a = *(const us4*)(gt + s0 * 32 + fq * 4);
#pragma unroll
            for (int c = 0; c < 4; ++c) acc[c] += bf2f(a[c]);
        }
#pragma unroll
        for (int m = 8; m <= 32; m <<= 1) {
#pragma unroll
            for (int c = 0; c < 4; ++c) acc[c] += __shfl_xor(acc[c], m, 64);
        }
        f4 pa = *(const f4*)(pacc + node * 32 + fq * 4);
        acc += pa;
        const float di = dinv[node];
        f4 hs;
        if (SELF32) {
            hs = *(const f4*)(hinf + node * 32 + fq * 4);
        } else {
            us4 hv = *(const us4*)(gt + node * 32 + fq * 4);
#pragma unroll
            for (int c = 0; c < 4; ++c) hs[c] = bf2f(hv[c]);
        }
        float x[4];
#pragma unroll
        for (int c = 0; c < 4; ++c) x[c] = half ? acc[c] * di : hs[c];
        float o = half ? 0.0f : sB[j];
#pragma unroll
        for (int k = 0; k < 32; ++k) {
            float v = __shfl(x[k & 3], (half << 5) + (k >> 2), 64);
            o += v * wt[k * OUTF + j];
        }
        o += __shfl_xor(o, 32, 64);
        if (lane < OUTF) {
            float s = 1.0f / (1.0f + __expf(-o));
            if (OUTBF) outb[node * OUTF + j] = f2bf(s);
            else outf[node * OUTF + j] = s;
        }
    }
}

// ---------------- launcher ----------------

extern "C" void kernel_launch(void* const* d_in, const int* in_sizes, int n_in,
                              void* d_out, int out_size, void* d_ws, size_t ws_size,
                              hipStream_t stream) {
    const float* inputs = (const float*)d_in[0];
    const int* src = (const int*)d_in[1];
    const int* dst = (const int*)d_in[2];
    const float* Ws1 = (const float*)d_in[3];
    const float* Wn1 = (const float*)d_in[4];
    const float* b1 = (const float*)d_in[5];
    const float* Ws2 = (const float*)d_in[6];
    const float* Wn2 = (const float*)d_in[7];
    const float* b2 = (const float*)d_in[8];
    const float* Ws3 = (const float*)d_in[9];
    const float* Wn3 = (const float*)d_in[10];
    const float* b3 = (const float*)d_in[11];
    float* out = (float*)d_out;

    int* ws = (int*)d_ws;
    int* degA = ws;                           // 100000
    int* degB = ws + 100000;                  // 100000 (dinv in-place after scan3)
    float* dinv = (float*)(ws + 100000);
    int* offs = ws + 200000;                  // 100001
    int* bnd = ws + 300016;                   // 100000
    int* bsums = ws + 400016;                 // 128
    int* ssrc = ws + 400160;                  // 1600000
    float* pacc = (float*)(ws + 2000160);     // 3200000 floats
    int* rank = ws + 2000160;                 // 800000 ints (dies before pacc live)
    unsigned short* gA = (unsigned short*)(ws + 5200160);  // 3.2M ushort
    unsigned short* gB = (unsigned short*)(ws + 6800160);  // 3.2M ushort

    hipMemsetAsync(degA, 0, 2 * NN * sizeof(int), stream);

    k_convert<<<3125, 256, 0, stream>>>((const f4*)inputs, (us4*)gA);
    const int egrid = (NE / 4 + 255) / 256;
    k_count<<<egrid, 256, 0, stream>>>((const i4*)dst, (const i4*)src, degA, degB,
                                       (us4*)rank);
    k_scan1<<<98, 256, 0, stream>>>(degA, degB, offs, bsums);
    k_scan2<<<1, 64, 0, stream>>>(bsums, 98);
    k_scan3<<<(NN + 255) / 256, 256, 0, stream>>>(offs, bsums, degA, degB, bnd, dinv);
    k_scatter<<<egrid, 256, 0, stream>>>((const i4*)src, (const i4*)dst,
                                         (const us4*)rank, offs, degA, ssrc);

    // layer1: gather gA (bf16 inputs), self fp32 inputs, out gB (bf16)
    k_sageA<<<2048, 256, 0, stream>>>(gA, offs, bnd, ssrc, pacc);
    k_sageB<32, true, true><<<2048, 256, 0, stream>>>(
        inputs, gA, offs, bnd, ssrc, dinv, pacc, Ws1, Wn1, b1, nullptr, gB);
    // layer2: gather gB, self gB, out gA (bf16)
    k_sageA<<<2048, 256, 0, stream>>>(gB, offs, bnd, ssrc, pacc);
    k_sageB<32, false, true><<<2048, 256, 0, stream>>>(
        nullptr, gB, offs, bnd, ssrc, dinv, pacc, Ws2, Wn2, b2, nullptr, gA);
    // layer3: gather gA, self gA, out fp32 d_out
    k_sageA<<<2048, 256, 0, stream>>>(gA, offs, bnd, ssrc, pacc);
    k_sageB<16, false, false><<<2048, 256, 0, stream>>>(
        nullptr, gA, offs, bnd, ssrc, dinv, pacc, Ws3, Wn3, b3, out, nullptr);
}